// Round 1
// baseline (283.575 us; speedup 1.0000x reference)
//
#include <hip/hip_runtime.h>
#include <math.h>

// idct_54271206752953: out[b,n,u,v] = 0.25 * sum_{x,y} img[b,n,x,y]*alpha[x,y]*basis[x,y,u,v] + 128
// Separable: out = D^T * S * D + 128, where D[x][u] = 0.5 * a[x] * cos((2u+1)*x*pi/16)
// (alpha[x,y]=a[x]*a[y] and the 0.25 split as 0.5*0.5 are folded into D).
// One thread per 8x8 block: 16 float4 loads, two 8x8 in-register matmuls
// (second pass overwrites staging array in place to cap VGPRs ~90), 16 float4 stores.
// Memory-bound: 268 MB traffic -> ~43us floor at 6.3 TB/s.

struct DMat { float d[64]; };  // passed by value -> kernarg -> SGPRs

__global__ __launch_bounds__(256) void idct_kernel(
    const float* __restrict__ img, float* __restrict__ out,
    DMat dm, int nblk)
{
    int m = blockIdx.x * 256 + threadIdx.x;
    if (m >= nblk) return;

    const float4* __restrict__ ip = (const float4*)(img + (size_t)m * 64);
    float s[64];
#pragma unroll
    for (int i = 0; i < 16; ++i) {
        float4 v = ip[i];
        s[4*i+0] = v.x; s[4*i+1] = v.y; s[4*i+2] = v.z; s[4*i+3] = v.w;
    }

    // Pass 1 (rows): s[x][v] <- sum_y s[x][y] * D[y][v], in place per row.
#pragma unroll
    for (int x = 0; x < 8; ++x) {
        float tt[8];
#pragma unroll
        for (int v = 0; v < 8; ++v) {
            float acc = 0.0f;
#pragma unroll
            for (int y = 0; y < 8; ++y)
                acc = fmaf(s[x*8+y], dm.d[y*8+v], acc);
            tt[v] = acc;
        }
#pragma unroll
        for (int v = 0; v < 8; ++v) s[x*8+v] = tt[v];
    }

    // Pass 2 (cols): out[u][v] = sum_x D[x][u] * s[x][v] + 128; store row immediately.
    float4* __restrict__ op = (float4*)(out + (size_t)m * 64);
#pragma unroll
    for (int u = 0; u < 8; ++u) {
        float o[8];
#pragma unroll
        for (int v = 0; v < 8; ++v) {
            float acc = 0.0f;
#pragma unroll
            for (int x = 0; x < 8; ++x)
                acc = fmaf(dm.d[x*8+u], s[x*8+v], acc);
            o[v] = acc + 128.0f;
        }
        float4 w0 = make_float4(o[0], o[1], o[2], o[3]);
        float4 w1 = make_float4(o[4], o[5], o[6], o[7]);
        op[u*2+0] = w0;
        op[u*2+1] = w1;
    }
}

extern "C" void kernel_launch(void* const* d_in, const int* in_sizes, int n_in,
                              void* d_out, int out_size, void* d_ws, size_t ws_size,
                              hipStream_t stream) {
    const float* img = (const float*)d_in[0];
    float* out = (float*)d_out;
    int nblk = in_sizes[0] / 64;  // 128*4096 = 524288 blocks of 8x8

    // Build D on host every call (graph-capture safe: identical values each call).
    DMat dm;
    const double PI = 3.14159265358979323846;
    for (int x = 0; x < 8; ++x) {
        double ax = (x == 0) ? (1.0 / sqrt(2.0)) : 1.0;
        for (int u = 0; u < 8; ++u)
            dm.d[x*8+u] = (float)(0.5 * ax * cos((2*u+1) * x * PI / 16.0));
    }

    int wg = (nblk + 255) / 256;
    idct_kernel<<<wg, 256, 0, stream>>>(img, out, dm, nblk);
}

// Round 2
// 235.307 us; speedup vs baseline: 1.2051x; 1.2051x over previous
//
#include <hip/hip_runtime.h>
#include <math.h>

// idct_54271206752953: out = D^T * S * D + 128 per 8x8 block, D[x][u] = 0.5*a[x]*cos((2u+1)x*pi/16).
//
// R2: fix write amplification (R1: WRITE_SIZE 234 MB vs 134 MB ideal, hbm 38% peak).
// One wave (64 threads) processes 64 consecutive blocks (16 KB):
//   global->LDS staging with fully-coalesced float4 (each instr = 1 KB contiguous,
//   full 128B lines), XOR-swizzled LDS layout addr = b*64 + (e ^ (b&31)):
//   - staging writes: bank = (e ^ swz) -> each bank exactly 2 lanes (free)
//   - compute reads (lane m, block m): bank = (i%32)^(m&31) -> exactly 2-way (free)
// Compute stays thread-per-block: 2 in-register 8x8 matmuls (1024 FMA/lane),
// pass2 column-in-place to cap VGPRs (~90). LDS = 16 KB -> 10 WGs/CU.

struct DMat { float d[64]; };  // by value -> kernarg -> SGPRs

__global__ __launch_bounds__(64) void idct64(
    const float* __restrict__ img, float* __restrict__ out, DMat dm)
{
    __shared__ float lds[4096];  // 64 blocks x 64 floats, xor-swizzled
    const int t = threadIdx.x;
    const size_t base = (size_t)blockIdx.x * 4096;  // floats

    // ---- stage in: 16 coalesced float4 loads, swizzled scatter to LDS ----
    const float4* __restrict__ ip = (const float4*)(img + base);
#pragma unroll
    for (int i = 0; i < 16; ++i) {
        float4 v = ip[i * 64 + t];
        int f = i * 64 + t;        // float4 index in chunk
        int b = f >> 4;            // block 0..63
        int e = (f & 15) << 2;     // element 0..60 (step 4)
        int sw = b & 31;
        float* p = lds + (b << 6);
        p[(e + 0) ^ sw] = v.x;
        p[(e + 1) ^ sw] = v.y;
        p[(e + 2) ^ sw] = v.z;
        p[(e + 3) ^ sw] = v.w;
    }
    __syncthreads();

    // ---- gather my block from LDS (2-way banked, free) ----
    float s[64];
    {
        const float* p = lds + (t << 6);
        int sw = t & 31;
#pragma unroll
        for (int i = 0; i < 64; ++i) s[i] = p[i ^ sw];
    }

    // ---- pass 1 (rows, in place): s[x][v] <- sum_y s[x][y] * D[y][v] ----
#pragma unroll
    for (int x = 0; x < 8; ++x) {
        float tt[8];
#pragma unroll
        for (int v = 0; v < 8; ++v) {
            float acc = 0.0f;
#pragma unroll
            for (int y = 0; y < 8; ++y)
                acc = fmaf(s[x * 8 + y], dm.d[y * 8 + v], acc);
            tt[v] = acc;
        }
#pragma unroll
        for (int v = 0; v < 8; ++v) s[x * 8 + v] = tt[v];
    }

    // ---- pass 2 (cols, in place per column): s[u][v] <- sum_x D[x][u]*s[x][v] + 128 ----
#pragma unroll
    for (int v = 0; v < 8; ++v) {
        float c[8];
#pragma unroll
        for (int x = 0; x < 8; ++x) c[x] = s[x * 8 + v];
#pragma unroll
        for (int u = 0; u < 8; ++u) {
            float acc = 0.0f;
#pragma unroll
            for (int x = 0; x < 8; ++x)
                acc = fmaf(c[x], dm.d[x * 8 + u], acc);
            s[u * 8 + v] = acc + 128.0f;
        }
    }

    // lane m only touches lds[m*64 .. m*64+64) here and only lane m read it above
    // -> no barrier needed before overwriting our own region.
    {
        float* p = lds + (t << 6);
        int sw = t & 31;
#pragma unroll
        for (int i = 0; i < 64; ++i) p[i ^ sw] = s[i];
    }
    __syncthreads();

    // ---- stage out: swizzled gather from LDS, 16 coalesced float4 stores ----
    float4* __restrict__ op = (float4*)(out + base);
#pragma unroll
    for (int i = 0; i < 16; ++i) {
        int f = i * 64 + t;
        int b = f >> 4;
        int e = (f & 15) << 2;
        int sw = b & 31;
        const float* p = lds + (b << 6);
        float4 v = make_float4(p[(e + 0) ^ sw], p[(e + 1) ^ sw],
                               p[(e + 2) ^ sw], p[(e + 3) ^ sw]);
        op[i * 64 + t] = v;
    }
}

// Scalar tail kernel (one thread per block) for nblk % 64 != 0 (unused at 524288).
__global__ __launch_bounds__(64) void idct_tail(
    const float* __restrict__ img, float* __restrict__ out, DMat dm,
    int first, int nblk)
{
    int m = first + blockIdx.x * 64 + threadIdx.x;
    if (m >= nblk) return;
    const float* ip = img + (size_t)m * 64;
    float s[64];
#pragma unroll
    for (int i = 0; i < 64; ++i) s[i] = ip[i];
#pragma unroll
    for (int x = 0; x < 8; ++x) {
        float tt[8];
#pragma unroll
        for (int v = 0; v < 8; ++v) {
            float acc = 0.0f;
#pragma unroll
            for (int y = 0; y < 8; ++y) acc = fmaf(s[x * 8 + y], dm.d[y * 8 + v], acc);
            tt[v] = acc;
        }
#pragma unroll
        for (int v = 0; v < 8; ++v) s[x * 8 + v] = tt[v];
    }
    float* opf = out + (size_t)m * 64;
#pragma unroll
    for (int v = 0; v < 8; ++v) {
        float c[8];
#pragma unroll
        for (int x = 0; x < 8; ++x) c[x] = s[x * 8 + v];
#pragma unroll
        for (int u = 0; u < 8; ++u) {
            float acc = 0.0f;
#pragma unroll
            for (int x = 0; x < 8; ++x) acc = fmaf(c[x], dm.d[x * 8 + u], acc);
            opf[u * 8 + v] = acc + 128.0f;
        }
    }
}

extern "C" void kernel_launch(void* const* d_in, const int* in_sizes, int n_in,
                              void* d_out, int out_size, void* d_ws, size_t ws_size,
                              hipStream_t stream) {
    const float* img = (const float*)d_in[0];
    float* out = (float*)d_out;
    int nblk = in_sizes[0] / 64;  // 524288

    DMat dm;
    const double PI = 3.14159265358979323846;
    for (int x = 0; x < 8; ++x) {
        double ax = (x == 0) ? (1.0 / sqrt(2.0)) : 1.0;
        for (int u = 0; u < 8; ++u)
            dm.d[x * 8 + u] = (float)(0.5 * ax * cos((2 * u + 1) * x * PI / 16.0));
    }

    int nwg = nblk / 64;          // full 64-block chunks
    int rem = nblk - nwg * 64;
    if (nwg > 0)
        idct64<<<nwg, 64, 0, stream>>>(img, out, dm);
    if (rem > 0)
        idct_tail<<<(rem + 63) / 64, 64, 0, stream>>>(img, out, dm, nwg * 64, nblk);
}

// Round 4
// 227.392 us; speedup vs baseline: 1.2471x; 1.0348x over previous
//
#include <hip/hip_runtime.h>
#include <math.h>

// idct_54271206752953: per 8x8 block, O = D^T * S * D + 128, D[x][u] = 0.5*a[x]*cos((2u+1)x*pi/16).
//
// R4 = R3 with the ds_swizzle pattern as a template parameter (compile-time
// constant requirement). Shape: 8 lanes per block, row-per-lane, NO LDS alloc,
// NO barriers:
//   - lane u of each 8-lane group loads/stores row u (2 float4); a wave covers
//     2KB contiguous both directions (each 128B line completed by adjacent lanes).
//   - pass 1 (S*D): lane-local, D from SGPRs (kernarg by value).
//   - pass 2 (D^T*T): ds_swizzle broadcast of lane x's row within the 8-group
//     (pattern (x<<5)|0x18: and=0x18 keeps group bits, or=x selects source lane);
//     per-lane D column built once via cndmask select tree.
//   - zero LDS + low VGPRs -> high occupancy, no sync.

struct DMat { float d[64]; };  // by value -> kernarg -> SGPRs

template <int PAT>
__device__ __forceinline__ float bcast8(float v) {
    return __int_as_float(__builtin_amdgcn_ds_swizzle(__float_as_int(v), PAT));
}

__global__ __launch_bounds__(256) void idct8(
    const float* __restrict__ img, float* __restrict__ out, DMat dm, int nblk)
{
    const int tid = blockIdx.x * 256 + threadIdx.x;
    const int u = tid & 7;                  // row within block
    const size_t blk = (size_t)(tid >> 3);  // one block per 8 lanes
    if (blk >= (size_t)nblk) return;        // group-uniform guard

    // ---- load my row (32B, two float4; wave = 2KB contiguous) ----
    const float* ip = img + blk * 64 + u * 8;
    float4 a = *(const float4*)ip;
    float4 b = *(const float4*)(ip + 4);
    float s[8] = {a.x, a.y, a.z, a.w, b.x, b.y, b.z, b.w};

    // ---- per-lane D column: col[x] = D[x][u], select tree per x ----
    float col[8];
    const bool u1 = (u & 1), u2 = (u & 2), u4 = (u & 4);
#pragma unroll
    for (int x = 0; x < 8; ++x) {
        float a01 = u1 ? dm.d[x * 8 + 1] : dm.d[x * 8 + 0];
        float a23 = u1 ? dm.d[x * 8 + 3] : dm.d[x * 8 + 2];
        float a45 = u1 ? dm.d[x * 8 + 5] : dm.d[x * 8 + 4];
        float a67 = u1 ? dm.d[x * 8 + 7] : dm.d[x * 8 + 6];
        float a03 = u2 ? a23 : a01;
        float a47 = u2 ? a67 : a45;
        col[x] = u4 ? a47 : a03;
    }

    // ---- pass 1 (lane-local): t[v] = sum_y s[y] * D[y][v]  (D from SGPRs) ----
    float t[8];
#pragma unroll
    for (int v = 0; v < 8; ++v) {
        float acc = 0.0f;
#pragma unroll
        for (int y = 0; y < 8; ++y)
            acc = fmaf(s[y], dm.d[y * 8 + v], acc);
        t[v] = acc;
    }

    // ---- pass 2: o[v] = sum_x D[x][u] * t_lane_x[v], via 8-group broadcast ----
    float o[8] = {0, 0, 0, 0, 0, 0, 0, 0};
#define P2STEP(X)                                                         \
    {                                                                     \
        constexpr int pat = ((X) << 5) | 0x18;                            \
        float cx = col[(X)];                                              \
        _Pragma("unroll")                                                 \
        for (int v = 0; v < 8; ++v)                                       \
            o[v] = fmaf(cx, bcast8<pat>(t[v]), o[v]);                     \
    }
    P2STEP(0) P2STEP(1) P2STEP(2) P2STEP(3)
    P2STEP(4) P2STEP(5) P2STEP(6) P2STEP(7)
#undef P2STEP

    // ---- store my row (+128) ----
    float* op = out + blk * 64 + u * 8;
    float4 w0 = make_float4(o[0] + 128.0f, o[1] + 128.0f, o[2] + 128.0f, o[3] + 128.0f);
    float4 w1 = make_float4(o[4] + 128.0f, o[5] + 128.0f, o[6] + 128.0f, o[7] + 128.0f);
    *(float4*)op = w0;
    *(float4*)(op + 4) = w1;
}

// Scalar tail (one thread per block) for nblk % 8 != 0 (unused at 524288).
__global__ __launch_bounds__(64) void idct_tail(
    const float* __restrict__ img, float* __restrict__ out, DMat dm,
    int first, int nblk)
{
    int m = first + blockIdx.x * 64 + threadIdx.x;
    if (m >= nblk) return;
    const float* ip = img + (size_t)m * 64;
    float s[64];
#pragma unroll
    for (int i = 0; i < 64; ++i) s[i] = ip[i];
#pragma unroll
    for (int x = 0; x < 8; ++x) {
        float tt[8];
#pragma unroll
        for (int v = 0; v < 8; ++v) {
            float acc = 0.0f;
#pragma unroll
            for (int y = 0; y < 8; ++y) acc = fmaf(s[x * 8 + y], dm.d[y * 8 + v], acc);
            tt[v] = acc;
        }
#pragma unroll
        for (int v = 0; v < 8; ++v) s[x * 8 + v] = tt[v];
    }
    float* opf = out + (size_t)m * 64;
#pragma unroll
    for (int v = 0; v < 8; ++v) {
        float c[8];
#pragma unroll
        for (int x = 0; x < 8; ++x) c[x] = s[x * 8 + v];
#pragma unroll
        for (int u = 0; u < 8; ++u) {
            float acc = 0.0f;
#pragma unroll
            for (int x = 0; x < 8; ++x) acc = fmaf(c[x], dm.d[x * 8 + u], acc);
            opf[u * 8 + v] = acc + 128.0f;
        }
    }
}

extern "C" void kernel_launch(void* const* d_in, const int* in_sizes, int n_in,
                              void* d_out, int out_size, void* d_ws, size_t ws_size,
                              hipStream_t stream) {
    const float* img = (const float*)d_in[0];
    float* out = (float*)d_out;
    int nblk = in_sizes[0] / 64;  // 524288

    DMat dm;
    const double PI = 3.14159265358979323846;
    for (int x = 0; x < 8; ++x) {
        double ax = (x == 0) ? (1.0 / sqrt(2.0)) : 1.0;
        for (int u = 0; u < 8; ++u)
            dm.d[x * 8 + u] = (float)(0.5 * ax * cos((2 * u + 1) * x * PI / 16.0));
    }

    int nMain = nblk & ~7;                 // blocks handled by idct8 (whole 8-groups)
    if (nMain > 0) {
        int threads = nMain * 8;           // 8 lanes per block
        int nwg = (threads + 255) / 256;
        idct8<<<nwg, 256, 0, stream>>>(img, out, dm, nMain);
    }
    int rem = nblk - nMain;
    if (rem > 0)
        idct_tail<<<(rem + 63) / 64, 64, 0, stream>>>(img, out, dm, nMain, nblk);
}